// Round 1
// 183.703 us; speedup vs baseline: 1.0864x; 1.0864x over previous
//
#include <hip/hip_runtime.h>
#include <hip/hip_bf16.h>

#define BATCH 32
#define LSEQ  512
#define NDIM  1024
#define NSPLIT 16

typedef __attribute__((ext_vector_type(8))) short bf16x8;
typedef __attribute__((ext_vector_type(4))) float f32x4;

__device__ __forceinline__ unsigned short f2bf(float x) {
    __hip_bfloat16 h = __float2bfloat16(x);
    return __builtin_bit_cast(unsigned short, h);
}

// ---------------------------------------------------------------------------
// Kernel 1: fused X fp32 -> bf16 conversion + s1/s2 partial sums (unchanged)
// ---------------------------------------------------------------------------
__global__ __launch_bounds__(256) void prep_kernel(
    const float* __restrict__ X, const float* __restrict__ W,
    unsigned short* __restrict__ Xb, float* __restrict__ P1, float* __restrict__ P2)
{
    __shared__ float sw[2 * LSEQ];
    int tid = threadIdx.x;
    for (int i = tid; i < 2 * LSEQ; i += 256) sw[i] = W[i];
    __syncthreads();

    int b  = blockIdx.y;
    int sp = blockIdx.x;
    int l0 = sp * (LSEQ / NSPLIT);
    size_t base = ((size_t)b * LSEQ + l0) * NDIM + tid * 4;
    const float* xp = X + base;
    unsigned short* xbp = Xb + base;

    float a0=0,a1=0,a2=0,a3=0, c0=0,c1=0,c2=0,c3=0;
    for (int l = 0; l < LSEQ / NSPLIT; ++l) {
        float4 x = *(const float4*)(xp + (size_t)l * NDIM);
        float w1 = sw[l0 + l], w2 = sw[LSEQ + l0 + l];
        a0 = fmaf(x.x, w1, a0); a1 = fmaf(x.y, w1, a1);
        a2 = fmaf(x.z, w1, a2); a3 = fmaf(x.w, w1, a3);
        c0 = fmaf(x.x, w2, c0); c1 = fmaf(x.y, w2, c1);
        c2 = fmaf(x.z, w2, c2); c3 = fmaf(x.w, w2, c3);
        ushort4 u; u.x = f2bf(x.x); u.y = f2bf(x.y); u.z = f2bf(x.z); u.w = f2bf(x.w);
        *(ushort4*)(xbp + (size_t)l * NDIM) = u;
    }
    size_t po = ((size_t)sp * BATCH + b) * NDIM + tid * 4;
    *(float4*)(P1 + po) = make_float4(a0, a1, a2, a3);
    *(float4*)(P2 + po) = make_float4(c0, c1, c2, c3);
}

// ---------------------------------------------------------------------------
// Kernel 2: fused reduce + softmax-denominator stats (unchanged)
// ---------------------------------------------------------------------------
__global__ __launch_bounds__(256) void stats_kernel(
    const float* __restrict__ P1, const float* __restrict__ P2,
    float* __restrict__ s1, float* __restrict__ s2, float* __restrict__ rd)
{
    __shared__ float s1s[NDIM];
    __shared__ float s2s[128];
    int t = threadIdx.x;
    int b = blockIdx.x >> 3, sl = blockIdx.x & 7;
    int j0 = sl * 128;

    #pragma unroll
    for (int q = 0; q < 4; ++q) {
        int n = q * 256 + t;
        float a = 0.f;
        #pragma unroll
        for (int sp = 0; sp < NSPLIT; ++sp)
            a += P1[((size_t)sp * BATCH + b) * NDIM + n];
        s1s[n] = a;
        if (sl == 0) s1[b * NDIM + n] = a;
    }
    if (t < 128) {
        int j = j0 + t;
        float c = 0.f;
        #pragma unroll
        for (int sp = 0; sp < NSPLIT; ++sp)
            c += P2[((size_t)sp * BATCH + b) * NDIM + j];
        s2s[t] = c;
        s2[b * NDIM + j] = c;
    }
    __syncthreads();

    int jl = t >> 1, half = t & 1;
    int jg = j0 + jl;
    float s2j = s2s[jl];
    float sum = 0.f;
    int i0 = half * 512;
    for (int i = i0; i < i0 + 512; ++i) {
        float v = s1s[i] + s2j;
        v = fmaxf(v, 0.01f * v);          // leaky relu
        if (i == jg) v = 0.f;             // diag of e zeroed before softmax
        sum += __expf(v);
    }
    sum += __shfl_xor(sum, 1);
    if (half == 0) rd[b * NDIM + jg] = 1.0f / sum;
}

// ---------------------------------------------------------------------------
// Kernel 3: Bt[b][i][j] = exp(e_ij) * rd[b,j] in bf16 (unchanged)
// ---------------------------------------------------------------------------
__global__ __launch_bounds__(256) void btgen_kernel(
    const float* __restrict__ s1, const float* __restrict__ s2,
    const float* __restrict__ rd, unsigned short* __restrict__ Bt)
{
    int wid = threadIdx.x >> 6, lane = threadIdx.x & 63;
    int r = blockIdx.x * 4 + wid;          // (b,i) flat
    int b = r >> 10, i = r & 1023;
    float s1i = s1[r];
    const float* s2b = s2 + b * NDIM;
    const float* rdb = rd + b * NDIM;
    unsigned short* outp = Bt + (size_t)r * NDIM;

    #pragma unroll
    for (int q = 0; q < 2; ++q) {
        int j0 = q * 512 + lane * 8;
        float sv[8], rv[8];
        #pragma unroll
        for (int h = 0; h < 2; ++h) {
            float4 s4 = *(const float4*)(s2b + j0 + h * 4);
            float4 r4 = *(const float4*)(rdb + j0 + h * 4);
            sv[h*4+0]=s4.x; sv[h*4+1]=s4.y; sv[h*4+2]=s4.z; sv[h*4+3]=s4.w;
            rv[h*4+0]=r4.x; rv[h*4+1]=r4.y; rv[h*4+2]=r4.z; rv[h*4+3]=r4.w;
        }
        bf16x8 v;
        #pragma unroll
        for (int k = 0; k < 8; ++k) {
            float e = s1i + sv[k];
            e = fmaxf(e, 0.01f * e);       // leaky relu
            if (j0 + k == i) e = 0.f;      // diag of e zeroed (alpha nonzero there)
            v[k] = (short)f2bf(__expf(e) * rv[k]);
        }
        *(bf16x8*)&outp[j0] = v;
    }
}

// ---------------------------------------------------------------------------
// Kernel 4: batched GEMM  out[b] = sigmoid( Xb[b] (512x1024) @ Bt[b]^T )
//
// NEW STRUCTURE (T2+T3+T4+T5 per regime-gate: counted-vmcnt pipeline is the
// prerequisite for swizzle/setprio to pay):
//   256x256 tile, 8 waves (2Mx4N), per-wave 128x64 output, BK=32.
//   LDS: 4 buffers x 256 composite rows x 128B (A-row 64B || B-row 64B)
//        = 128 KiB, XOR-swizzled: byte ^= ((row&7)<<4).
//        Staged via global_load_lds with PRE-SWIZZLED per-lane global source
//        (linear LDS dest, rule #21) -> ds_read_b128 spreads 32 banks, ~2-way.
//   Pipeline: 3-tile prefetch lead; ONE raw s_barrier per K-tile; counted
//        s_waitcnt vmcnt(8) steady state (never 0 until epilogue 8->4->0).
//        No __syncthreads in the loop => no compiler vmcnt(0) drain.
//   Correctness: wave waits vmcnt for ITS tile-t loads BEFORE the barrier;
//        barrier publishes all waves' stages. Buffer (t+3)&3 was last read at
//        iter t-1; those ds_reads retire (register waits) before any wave
//        reaches iter t's barrier, so stage-after-barrier is WAR-safe.
// ---------------------------------------------------------------------------
#define WAITVM(n) asm volatile("s_waitcnt vmcnt(" #n ")" ::: "memory")
#define FENCE()   asm volatile("" ::: "memory")

#define DO_STAGE(bufi) {                                                        \
    _Pragma("unroll")                                                           \
    for (int j = 0; j < 4; ++j) {                                               \
        __builtin_amdgcn_global_load_lds(                                       \
            (const __attribute__((address_space(1))) void*)srcp[j],             \
            (__attribute__((address_space(3))) void*)(LdsC + (bufi) * 32768 +   \
                                                      ldst0 + j * 8192),        \
            16, 0, 0);                                                          \
        srcp[j] += 64;  /* advance k by 32 bf16 per tile */                     \
    } }

#define COMPUTE(bufi) {                                                         \
    const char* Lb = LdsC + (bufi) * 32768;                                     \
    bf16x8 av[8]; bf16x8 bv[4];                                                 \
    _Pragma("unroll")                                                           \
    for (int mi = 0; mi < 8; ++mi)                                              \
        av[mi] = *(const bf16x8*)(Lb + abase0 + mi * 2048);                     \
    _Pragma("unroll")                                                           \
    for (int ni = 0; ni < 4; ++ni)                                              \
        bv[ni] = *(const bf16x8*)(Lb + bbase0 + ni * 2048);                     \
    __builtin_amdgcn_s_setprio(1);                                              \
    _Pragma("unroll")                                                           \
    for (int ni = 0; ni < 4; ++ni)                                              \
        _Pragma("unroll")                                                       \
        for (int mi = 0; mi < 8; ++mi)                                          \
            acc[mi][ni] = __builtin_amdgcn_mfma_f32_16x16x32_bf16(              \
                av[mi], bv[ni], acc[mi][ni], 0, 0, 0);                          \
    __builtin_amdgcn_s_setprio(0);                                              \
}

__global__ __launch_bounds__(512, 2) void gemm_kernel(
    const unsigned short* __restrict__ Xb, const unsigned short* __restrict__ Bt,
    float* __restrict__ out)
{
    // 4 buffers x 256 rows x 128 B = 128 KiB
    __shared__ __align__(16) unsigned short LDSU[65536];
    char* LdsC = (char*)LDSU;

    const int tid = threadIdx.x, lane = tid & 63, wid = tid >> 6;
    const int wm = wid >> 2, wn = wid & 3;      // 2 x 4 wave grid

    // block mapping: 8 blocks/batch all on one XCD (flat&7 == b&7),
    // 4 batches per XCD, grid 256 = exactly 1 block/CU.
    int flat  = blockIdx.x;
    int xcd   = flat & 7;
    int p     = flat >> 3;
    int b     = (p >> 3) * 8 + xcd;
    int inner = p & 7;
    int mt = inner & 1, nt = inner >> 1;
    int l0 = mt * 256, n0 = nt * 256;

    const char* XgB = (const char*)(Xb + ((size_t)b * LSEQ + l0) * NDIM);
    const char* BgB = (const char*)(Bt + ((size_t)b * NDIM + n0) * NDIM);

    // Staging: chunk c = tid + j*512 fills LDS bytes [c*16, c*16+16).
    // Composite row r = c>>3 (128 B: logical A 0..63 | B 64..127), slot = c&7.
    // Physical slot holds logical offset (slot*16) ^ ((r&7)<<4)  [involution].
    const char* srcp[4];
    #pragma unroll
    for (int j = 0; j < 4; ++j) {
        int c = tid + j * 512;
        int r = c >> 3, slot = c & 7;
        int off = (slot * 16) ^ ((r & 7) << 4);
        srcp[j] = (off < 64) ? XgB + (size_t)r * 2048 + off
                             : BgB + (size_t)r * 2048 + (off - 64);
    }
    const int ldst0 = wid * 1024;               // uniform LDS dest base (+j*8192+buf*32768)

    // Fragment read offsets (swizzled). r&7 == rsel&7 for all fragments, so
    // swz is a per-lane constant and mi/ni strides fold to ds_read immediates.
    const int rsel = lane & 15, kq = lane >> 4;
    const int swz  = (rsel & 7) << 4;
    const int abase0 = wm * 16384 + rsel * 128 + ((kq * 16) ^ swz);
    const int bbase0 = wn * 8192  + rsel * 128 + (((64 + kq * 16)) ^ swz);

    f32x4 acc[8][4] = {};

    // prologue: 3-tile lead (12 loads/thread outstanding)
    DO_STAGE(0); DO_STAGE(1); DO_STAGE(2);

    // main loop: tiles 0..28 stage t+3; vmcnt(8) leaves tiles t+1,t+2 in flight
    for (int t = 0; t < 29; ++t) {
        WAITVM(8);
        __builtin_amdgcn_s_barrier();
        FENCE();
        DO_STAGE((t + 3) & 3);
        COMPUTE(t & 3);
    }
    // epilogue: drain 8 -> 4 -> 0 (tiles 29,30,31; no more stages)
    WAITVM(8); __builtin_amdgcn_s_barrier(); FENCE(); COMPUTE(1);
    WAITVM(4); __builtin_amdgcn_s_barrier(); FENCE(); COMPUTE(2);
    WAITVM(0); __builtin_amdgcn_s_barrier(); FENCE(); COMPUTE(3);

    // epilogue: C/D layout col=lane&15, row=(lane>>4)*4+reg  [m89/m91 verified]
    float* outb = out + ((size_t)b * LSEQ + l0) * NDIM + n0;
    const int rq = lane >> 4, cl = lane & 15;
    #pragma unroll
    for (int mi = 0; mi < 8; ++mi)
        #pragma unroll
        for (int ni = 0; ni < 4; ++ni) {
            int col = wn * 64 + ni * 16 + cl;
            #pragma unroll
            for (int r2 = 0; r2 < 4; ++r2) {
                int row = wm * 128 + mi * 16 + rq * 4 + r2;
                float v = acc[mi][ni][r2];
                outb[(size_t)row * NDIM + col] = 1.0f / (1.0f + __expf(-v));
            }
        }
}

#undef WAITVM
#undef FENCE
#undef DO_STAGE
#undef COMPUTE

// ---------------------------------------------------------------------------
extern "C" void kernel_launch(void* const* d_in, const int* in_sizes, int n_in,
                              void* d_out, int out_size, void* d_ws, size_t ws_size,
                              hipStream_t stream) {
    (void)in_sizes; (void)n_in; (void)out_size; (void)ws_size;
    const float* X = (const float*)d_in[0];
    const float* W = (const float*)d_in[1];
    float* out = (float*)d_out;

    // workspace: s1|s2|rd (32K floats each) | P1|P2 (512K floats each)
    //            | Xb bf16 32MB | Bt bf16 64MB   (~100.4 MB, same as before)
    float* s1 = (float*)d_ws;
    float* s2 = s1 + BATCH * NDIM;
    float* rd = s2 + BATCH * NDIM;
    float* P1 = rd + BATCH * NDIM;
    float* P2 = P1 + (size_t)NSPLIT * BATCH * NDIM;
    unsigned short* Xb = (unsigned short*)(P2 + (size_t)NSPLIT * BATCH * NDIM);
    unsigned short* Bt = Xb + (size_t)BATCH * LSEQ * NDIM;

    prep_kernel<<<dim3(NSPLIT, BATCH), 256, 0, stream>>>(X, W, Xb, P1, P2);
    stats_kernel<<<256, 256, 0, stream>>>(P1, P2, s1, s2, rd);
    btgen_kernel<<<(BATCH * NDIM) / 4, 256, 0, stream>>>(s1, s2, rd, Bt);
    gemm_kernel<<<256, 512, 0, stream>>>(Xb, Bt, out);
}